// Round 1
// baseline (1617.854 us; speedup 1.0000x reference)
//
#include <hip/hip_runtime.h>

#define NROWS 65536

// C[M,Nc] = act(A[M,K] @ W[K,Nc] + bias), tile 64x64, 256 threads, 4x4/thread.
__global__ void gemm_bias_act(const float* __restrict__ A, const float* __restrict__ W,
                              const float* __restrict__ bias, float* __restrict__ C,
                              int K, int Nc, int sig) {
  __shared__ float As[16][65];   // [k][m], +1 pad breaks transposed-store conflicts
  __shared__ float Ws[16][64];   // [k][n]
  const int tid = threadIdx.x;
  const int m0 = blockIdx.x * 64;
  const int n0 = blockIdx.y * 64;
  const int tx = tid & 15, ty = tid >> 4;
  float acc[4][4] = {};
  for (int k0 = 0; k0 < K; k0 += 16) {
    {
      const int e = tid * 4;
      const int m = e >> 4;
      const int k = e & 15;   // multiple of 4
      const float4 av = *(const float4*)(A + (size_t)(m0 + m) * K + (k0 + k));
      As[k + 0][m] = av.x;
      As[k + 1][m] = av.y;
      As[k + 2][m] = av.z;
      As[k + 3][m] = av.w;
    }
    {
      const int e = tid * 4;
      const int kk = e >> 6;
      const int n = e & 63;   // multiple of 4
      *(float4*)(&Ws[kk][n]) = *(const float4*)(W + (size_t)(k0 + kk) * Nc + (n0 + n));
    }
    __syncthreads();
#pragma unroll
    for (int kk = 0; kk < 16; ++kk) {
      float a[4], b[4];
#pragma unroll
      for (int i = 0; i < 4; ++i) a[i] = As[kk][ty * 4 + i];
#pragma unroll
      for (int j = 0; j < 4; ++j) b[j] = Ws[kk][tx * 4 + j];
#pragma unroll
      for (int i = 0; i < 4; ++i)
#pragma unroll
        for (int j = 0; j < 4; ++j) acc[i][j] += a[i] * b[j];
    }
    __syncthreads();
  }
#pragma unroll
  for (int i = 0; i < 4; ++i) {
    const int m = m0 + ty * 4 + i;
    float4 v;
    float* pv = &v.x;
#pragma unroll
    for (int j = 0; j < 4; ++j) {
      float val = acc[i][j] + bias[n0 + tx * 4 + j];
      if (sig) val = 1.0f / (1.0f + __expf(-val));
      pv[j] = val;
    }
    *(float4*)(C + (size_t)m * Nc + (n0 + tx * 4)) = v;
  }
}

// Cout[Ap,Bq] += sum_n f(P[n,a]) * f(Q[n,b]), f(h)=h*(1-h). Split-K over grid.z.
__global__ void covar_kernel(const float* __restrict__ P, const float* __restrict__ Q,
                             float* __restrict__ Cout, int Ap, int Bq, int chunk) {
  __shared__ float Ps[16][65];
  __shared__ float Qs[16][65];
  const int tid = threadIdx.x;
  const int a0 = blockIdx.x * 64;
  const int b0 = blockIdx.y * 64;
  const int nbase = blockIdx.z * chunk;
  const int tx = tid & 15, ty = tid >> 4;
  float acc[4][4] = {};
  for (int nn = 0; nn < chunk; nn += 16) {
    const int e = tid * 4;
    const int r = e >> 6;
    const int c = e & 63;
    {
      const float4 v = *(const float4*)(P + (size_t)(nbase + nn + r) * Ap + (a0 + c));
      Ps[r][c + 0] = v.x * (1.0f - v.x);
      Ps[r][c + 1] = v.y * (1.0f - v.y);
      Ps[r][c + 2] = v.z * (1.0f - v.z);
      Ps[r][c + 3] = v.w * (1.0f - v.w);
    }
    {
      const float4 u = *(const float4*)(Q + (size_t)(nbase + nn + r) * Bq + (b0 + c));
      Qs[r][c + 0] = u.x * (1.0f - u.x);
      Qs[r][c + 1] = u.y * (1.0f - u.y);
      Qs[r][c + 2] = u.z * (1.0f - u.z);
      Qs[r][c + 3] = u.w * (1.0f - u.w);
    }
    __syncthreads();
#pragma unroll
    for (int kk = 0; kk < 16; ++kk) {
      float a[4], b[4];
#pragma unroll
      for (int i = 0; i < 4; ++i) a[i] = Ps[kk][ty * 4 + i];
#pragma unroll
      for (int j = 0; j < 4; ++j) b[j] = Qs[kk][tx * 4 + j];
#pragma unroll
      for (int i = 0; i < 4; ++i)
#pragma unroll
        for (int j = 0; j < 4; ++j) acc[i][j] += a[i] * b[j];
    }
    __syncthreads();
  }
#pragma unroll
  for (int i = 0; i < 4; ++i)
#pragma unroll
    for (int j = 0; j < 4; ++j)
      atomicAdd(&Cout[(size_t)(a0 + ty * 4 + i) * Bq + (b0 + tx * 4 + j)], acc[i][j]);
}

// z = h2e @ W2 + b2 ; theta(z) ; dzb = theta @ Ew + Eb.  One wave per row.
__global__ void enc_l3_sindy(const float* __restrict__ h2, const float* __restrict__ W2,
                             const float* __restrict__ b2, const float* __restrict__ Ew,
                             const float* __restrict__ Eb, float* __restrict__ z_out,
                             float* __restrict__ dzb_out) {
  const int lane = threadIdx.x & 63;
  const int row = blockIdx.x * 4 + (threadIdx.x >> 6);
  const float2 h = *(const float2*)(h2 + (size_t)row * 128 + lane * 2);
  const int k = lane * 2;
  float s[3];
#pragma unroll
  for (int l = 0; l < 3; ++l)
    s[l] = h.x * W2[k * 3 + l] + h.y * W2[(k + 1) * 3 + l];
#pragma unroll
  for (int off = 32; off > 0; off >>= 1) {
    s[0] += __shfl_xor(s[0], off);
    s[1] += __shfl_xor(s[1], off);
    s[2] += __shfl_xor(s[2], off);
  }
  if (lane == 0) {
    const float z0 = s[0] + b2[0];
    const float z1 = s[1] + b2[1];
    const float z2 = s[2] + b2[2];
    z_out[row * 3 + 0] = z0;
    z_out[row * 3 + 1] = z1;
    z_out[row * 3 + 2] = z2;
    float th[22];
    th[0] = 1.f; th[1] = 1.f; th[2] = 1.f;
    th[3] = z0; th[4] = z1; th[5] = z2;
    th[6] = z0 * z0; th[7] = z0 * z1; th[8] = z0 * z2;
    th[9] = z1 * z1; th[10] = z1 * z2; th[11] = z2 * z2;
    th[12] = z0 * z0 * z0; th[13] = z0 * z0 * z1; th[14] = z0 * z0 * z2;
    th[15] = z0 * z1 * z1; th[16] = z0 * z1 * z2; th[17] = z0 * z2 * z2;
    th[18] = z1 * z1 * z1; th[19] = z1 * z1 * z2; th[20] = z1 * z2 * z2;
    th[21] = z2 * z2 * z2;
    float d0 = Eb[0], d1 = Eb[1], d2 = Eb[2];
#pragma unroll
    for (int c = 0; c < 22; ++c) {
      d0 += th[c] * Ew[c * 3 + 0];
      d1 += th[c] * Ew[c * 3 + 1];
      d2 += th[c] * Ew[c * 3 + 2];
    }
    dzb_out[row * 3 + 0] = d0;
    dzb_out[row * 3 + 1] = d1;
    dzb_out[row * 3 + 2] = d2;
  }
}

// T1[l,b] = (1/N) * sum_a W2[a,l] * W1[b,a] * Ce[a,b]
__global__ void t1_kernel(const float* __restrict__ Ce, const float* __restrict__ W2,
                          const float* __restrict__ W1, float* __restrict__ T1) {
  const int l = blockIdx.x;
  const int b = threadIdx.x;  // 0..255
  float acc = 0.f;
  for (int a = 0; a < 128; ++a)
    acc += W2[a * 3 + l] * W1[b * 128 + a] * Ce[a * 256 + b];
  T1[l * 256 + b] = acc * (1.0f / 65536.0f);
}

// Je[l,k] = sum_b T1[l,b] * W0[k,b]
__global__ void je_kernel(const float* __restrict__ T1, const float* __restrict__ W0,
                          float* __restrict__ Je) {
  const int k = blockIdx.x * 256 + threadIdx.x;  // 0..511
  const int l = blockIdx.y;
  float acc = 0.f;
  for (int b = 0; b < 256; ++b) acc += T1[l * 256 + b] * W0[(size_t)k * 256 + b];
  Je[l * 512 + k] = acc;
}

// T2[a,l] = (1/N) * sum_b Cd[a,b] * V1[b,a] * V0[l,b]
__global__ void t2_kernel(const float* __restrict__ Cd, const float* __restrict__ V1,
                          const float* __restrict__ V0, float* __restrict__ T2) {
  const int l = blockIdx.x;
  const int a = threadIdx.x;  // 0..255
  float acc = 0.f;
  for (int b = 0; b < 128; ++b)
    acc += Cd[a * 128 + b] * V1[b * 256 + a] * V0[l * 128 + b];
  T2[a * 3 + l] = acc * (1.0f / 65536.0f);
}

// Jd[k,l] = sum_a V2[a,k] * T2[a,l]
__global__ void jd_kernel(const float* __restrict__ T2, const float* __restrict__ V2,
                          float* __restrict__ Jd) {
  const int k = blockIdx.x * 256 + threadIdx.x;
  const int l = blockIdx.y;
  float acc = 0.f;
  for (int a = 0; a < 256; ++a) acc += V2[(size_t)a * 512 + k] * T2[a * 3 + l];
  Jd[k * 3 + l] = acc;
}

// dz[n,l] = sum_k dx[n,k] * Je[l,k].  One wave per row, 8 floats/lane.
__global__ void dz_kernel(const float* __restrict__ dx, const float* __restrict__ Je,
                          float* __restrict__ dz) {
  __shared__ float sJe[1536];
  for (int i = threadIdx.x; i < 1536; i += 256) sJe[i] = Je[i];
  __syncthreads();
  const int lane = threadIdx.x & 63;
  const int row = blockIdx.x * 4 + (threadIdx.x >> 6);
  const int k = lane * 8;
  const float4 v0 = *(const float4*)(dx + (size_t)row * 512 + k);
  const float4 v1 = *(const float4*)(dx + (size_t)row * 512 + k + 4);
  float s[3];
#pragma unroll
  for (int l = 0; l < 3; ++l) {
    const float* j = sJe + l * 512 + k;
    s[l] = v0.x * j[0] + v0.y * j[1] + v0.z * j[2] + v0.w * j[3] +
           v1.x * j[4] + v1.y * j[5] + v1.z * j[6] + v1.w * j[7];
  }
#pragma unroll
  for (int off = 32; off > 0; off >>= 1) {
    s[0] += __shfl_xor(s[0], off);
    s[1] += __shfl_xor(s[1], off);
    s[2] += __shfl_xor(s[2], off);
  }
  if (lane == 0) {
    dz[row * 3 + 0] = s[0];
    dz[row * 3 + 1] = s[1];
    dz[row * 3 + 2] = s[2];
  }
}

// h1d[n,j] = sigmoid(sum_l z[n,l]*V0[l,j] + b0[j]), j<128
__global__ void dec_l1(const float* __restrict__ z, const float* __restrict__ V0,
                       const float* __restrict__ b0, float* __restrict__ h1d) {
  __shared__ float sW[512];
  for (int i = threadIdx.x; i < 512; i += 256)
    sW[i] = (i < 384) ? V0[i] : b0[i - 384];
  __syncthreads();
  const int idx = blockIdx.x * 256 + threadIdx.x;
  const int n = idx >> 7;
  const int j = idx & 127;
  const float z0 = z[n * 3 + 0], z1 = z[n * 3 + 1], z2 = z[n * 3 + 2];
  const float v = z0 * sW[j] + z1 * sW[128 + j] + z2 * sW[256 + j] + sW[384 + j];
  h1d[idx] = 1.0f / (1.0f + __expf(-v));
}

// dxb[n,k] = sum_l dzb[n,l] * Jd[k,l]
__global__ void dxb_kernel(const float* __restrict__ dzb, const float* __restrict__ Jd,
                           float* __restrict__ dxb) {
  __shared__ float sJd[1536];
  for (int i = threadIdx.x; i < 1536; i += 256) sJd[i] = Jd[i];
  __syncthreads();
  const int idx = blockIdx.x * 256 + threadIdx.x;
  const int n = idx >> 9;
  const int k = idx & 511;
  const float d0 = dzb[n * 3 + 0], d1 = dzb[n * 3 + 1], d2 = dzb[n * 3 + 2];
  dxb[idx] = d0 * sJd[k * 3 + 0] + d1 * sJd[k * 3 + 1] + d2 * sJd[k * 3 + 2];
}

extern "C" void kernel_launch(void* const* d_in, const int* in_sizes, int n_in,
                              void* d_out, int out_size, void* d_ws, size_t ws_size,
                              hipStream_t stream) {
  const int N = NROWS;
  const float* x   = (const float*)d_in[0];
  const float* dx  = (const float*)d_in[1];
  // d_in[2] = ddx, unused by outputs
  const float* eW0 = (const float*)d_in[3];
  const float* eb0 = (const float*)d_in[4];
  const float* eW1 = (const float*)d_in[5];
  const float* eb1 = (const float*)d_in[6];
  const float* eW2 = (const float*)d_in[7];
  const float* eb2 = (const float*)d_in[8];
  const float* dW0 = (const float*)d_in[9];
  const float* db0 = (const float*)d_in[10];
  const float* dW1 = (const float*)d_in[11];
  const float* db1 = (const float*)d_in[12];
  const float* dW2 = (const float*)d_in[13];
  const float* db2 = (const float*)d_in[14];
  const float* Ew  = (const float*)d_in[15];
  const float* Eb  = (const float*)d_in[16];

  float* out = (float*)d_out;
  float* z_out   = out;
  float* dz_out  = out + (size_t)N * 3;
  float* dzb_out = out + (size_t)N * 6;
  float* xb_out  = out + (size_t)N * 9;
  float* dxb_out = out + (size_t)N * 9 + (size_t)N * 512;

  float* wsf = (float*)d_ws;
  float* buf256 = wsf;                       // N*256 : h1e, later h2d
  float* buf128 = wsf + (size_t)N * 256;     // N*128 : h2e, later h1d
  float* Ce = wsf + (size_t)N * 384;         // 128*256
  float* Cd = Ce + 128 * 256;                // 256*128
  float* T1 = Cd + 256 * 128;                // 3*256
  float* T2 = T1 + 3 * 256;                  // 256*3
  float* Je = T2 + 256 * 3;                  // 3*512
  float* Jd = Je + 3 * 512;                  // 512*3

  // zero the covariance accumulators (ws is poisoned 0xAA before each call)
  hipMemsetAsync(Ce, 0, (size_t)(128 * 256 + 256 * 128) * sizeof(float), stream);

  // encoder forward
  gemm_bias_act<<<dim3(N / 64, 4), 256, 0, stream>>>(x, eW0, eb0, buf256, 512, 256, 1);
  gemm_bias_act<<<dim3(N / 64, 2), 256, 0, stream>>>(buf256, eW1, eb1, buf128, 256, 128, 1);
  enc_l3_sindy<<<N / 4, 256, 0, stream>>>(buf128, eW2, eb2, Ew, Eb, z_out, dzb_out);

  // encoder mean-Jacobian
  covar_kernel<<<dim3(2, 4, 32), 256, 0, stream>>>(buf128, buf256, Ce, 128, 256, 2048);
  t1_kernel<<<3, 256, 0, stream>>>(Ce, eW2, eW1, T1);
  je_kernel<<<dim3(2, 3), 256, 0, stream>>>(T1, eW0, Je);
  dz_kernel<<<N / 4, 256, 0, stream>>>(dx, Je, dz_out);

  // decoder forward (reuses buffers; covar on encoder acts already done)
  dec_l1<<<N * 128 / 256, 256, 0, stream>>>(z_out, dW0, db0, buf128);
  gemm_bias_act<<<dim3(N / 64, 4), 256, 0, stream>>>(buf128, dW1, db1, buf256, 128, 256, 1);
  gemm_bias_act<<<dim3(N / 64, 8), 256, 0, stream>>>(buf256, dW2, db2, xb_out, 256, 512, 0);

  // decoder mean-Jacobian
  covar_kernel<<<dim3(4, 2, 32), 256, 0, stream>>>(buf256, buf128, Cd, 256, 128, 2048);
  t2_kernel<<<3, 256, 0, stream>>>(Cd, dW1, dW0, T2);
  jd_kernel<<<dim3(2, 3), 256, 0, stream>>>(T2, dW2, Jd);
  dxb_kernel<<<N * 512 / 256, 256, 0, stream>>>(dzb_out, Jd, dxb_out);
}

// Round 2
// 967.380 us; speedup vs baseline: 1.6724x; 1.6724x over previous
//
#include <hip/hip_runtime.h>

#define NROWS 65536

typedef unsigned short u16;
typedef short bf16x8 __attribute__((ext_vector_type(8)));    // 8 bf16 in 4 VGPRs (MFMA operand)
typedef u16 u16x8 __attribute__((ext_vector_type(8)));
typedef float f32x4 __attribute__((ext_vector_type(4)));

__device__ __forceinline__ u16 f2bf(float f) {
  unsigned int u = __builtin_bit_cast(unsigned int, f);
  u += 0x7FFFu + ((u >> 16) & 1u);   // round-to-nearest-even
  return (u16)(u >> 16);
}
__device__ __forceinline__ float bf2f(u16 s) {
  return __builtin_bit_cast(float, (unsigned int)s << 16);
}

// ---------------------------------------------------------------------------
// Weight prep: bf16 + transpose -> Wt[Nc][K] so B staging is k-contiguous.
// ---------------------------------------------------------------------------
__global__ void prep_weights(const float* __restrict__ eW0, const float* __restrict__ eW1,
                             const float* __restrict__ dW1, const float* __restrict__ dW2,
                             u16* __restrict__ eW0t, u16* __restrict__ eW1t,
                             u16* __restrict__ dW1t, u16* __restrict__ dW2t) {
  const int idx = blockIdx.x * 256 + threadIdx.x;
  if (idx < 131072) {                       // eW0 [512][256] -> eW0t[256][512]
    const int n = idx >> 9, k = idx & 511;
    eW0t[idx] = f2bf(eW0[k * 256 + n]);
  } else if (idx < 163840) {                // eW1 [256][128] -> eW1t[128][256]
    const int j = idx - 131072, n = j >> 8, k = j & 255;
    eW1t[j] = f2bf(eW1[k * 128 + n]);
  } else if (idx < 196608) {                // dW1 [128][256] -> dW1t[256][128]
    const int j = idx - 163840, n = j >> 7, k = j & 127;
    dW1t[j] = f2bf(dW1[k * 256 + n]);
  } else {                                  // dW2 [256][512] -> dW2t[512][256]
    const int j = idx - 196608, n = j >> 8, k = j & 255;
    dW2t[j] = f2bf(dW2[k * 512 + n]);
  }
}

// ---------------------------------------------------------------------------
// MFMA GEMM: C[M,Nc] = act(A[M,K] @ W[K,Nc] + bias).
// A bf16 [M][K] (or fp32 converted in staging), Wt bf16 [Nc][K].
// Block: 128x128 tile, 256 threads = 4 waves (2x2 of 64x64), 16x16x32 MFMA.
// grid = (Nc/128, M/128)  -- n fastest for A-tile L2 reuse.
// LDS k-chunks XOR-swizzled by (row>>1)&3 to break ds_read_b128 bank aliasing.
// ---------------------------------------------------------------------------
template <int ACT, int A_F32>
__global__ __launch_bounds__(256, 2) void gemm_mfma(const void* __restrict__ Av,
                                                    const u16* __restrict__ Wt,
                                                    const float* __restrict__ bias,
                                                    void* __restrict__ Cv, int K, int Nc) {
  __shared__ u16 As[128 * 32];
  __shared__ u16 Bs[128 * 32];
  const int tid = threadIdx.x;
  const int lane = tid & 63;
  const int wave = tid >> 6;
  const int n0 = blockIdx.x * 128;
  const int m0 = blockIdx.y * 128;
  const int wm = (wave & 1) * 64;
  const int wn = (wave >> 1) * 64;
  const int q = lane >> 4;       // k-group 0..3
  const int mr = lane & 15;

  f32x4 acc[4][4] = {};

  for (int k0 = 0; k0 < K; k0 += 32) {
    // ---- stage A tile [128 rows][32 k] ----
    if (A_F32) {
      const float* A = (const float*)Av;
#pragma unroll
      for (int i = 0; i < 2; ++i) {
        const int c = tid + i * 256;           // 16B chunk id
        const int r = c >> 2, p = c & 3;
        const int g = (p - (r >> 1)) & 3;      // swizzled global k-chunk
        const float* src = A + (size_t)(m0 + r) * K + k0 + g * 8;
        const float4 v0 = *(const float4*)src;
        const float4 v1 = *(const float4*)(src + 4);
        u16x8 w;
        w[0] = f2bf(v0.x); w[1] = f2bf(v0.y); w[2] = f2bf(v0.z); w[3] = f2bf(v0.w);
        w[4] = f2bf(v1.x); w[5] = f2bf(v1.y); w[6] = f2bf(v1.z); w[7] = f2bf(v1.w);
        *(u16x8*)&As[c * 8] = w;
      }
    } else {
      const u16* A = (const u16*)Av;
#pragma unroll
      for (int i = 0; i < 2; ++i) {
        const int c = tid + i * 256;
        const int r = c >> 2, p = c & 3;
        const int g = (p - (r >> 1)) & 3;
        __builtin_amdgcn_global_load_lds(
            (const __attribute__((address_space(1))) void*)(A + (size_t)(m0 + r) * K + k0 + g * 8),
            (__attribute__((address_space(3))) void*)&As[(i * 256 + wave * 64) * 8], 16, 0, 0);
      }
    }
    // ---- stage B tile: Wt rows n0..n0+127, k chunk ----
    {
#pragma unroll
      for (int i = 0; i < 2; ++i) {
        const int c = tid + i * 256;
        const int r = c >> 2, p = c & 3;
        const int g = (p - (r >> 1)) & 3;
        __builtin_amdgcn_global_load_lds(
            (const __attribute__((address_space(1))) void*)(Wt + (size_t)(n0 + r) * K + k0 + g * 8),
            (__attribute__((address_space(3))) void*)&Bs[(i * 256 + wave * 64) * 8], 16, 0, 0);
      }
    }
    __syncthreads();

    bf16x8 af[4], bfr[4];
#pragma unroll
    for (int i = 0; i < 4; ++i) {
      const int r = wm + i * 16 + mr;
      const int col = (q + (r >> 1)) & 3;
      af[i] = *(const bf16x8*)&As[r * 32 + col * 8];
    }
#pragma unroll
    for (int j = 0; j < 4; ++j) {
      const int r = wn + j * 16 + mr;
      const int col = (q + (r >> 1)) & 3;
      bfr[j] = *(const bf16x8*)&Bs[r * 32 + col * 8];
    }
#pragma unroll
    for (int i = 0; i < 4; ++i)
#pragma unroll
      for (int j = 0; j < 4; ++j)
        acc[i][j] = __builtin_amdgcn_mfma_f32_16x16x32_bf16(af[i], bfr[j], acc[i][j], 0, 0, 0);
    __syncthreads();
  }

  // ---- epilogue: C/D layout col=lane&15, row=(lane>>4)*4+reg ----
  const int orow = (lane >> 4) * 4;
  const int ocol = lane & 15;
#pragma unroll
  for (int j = 0; j < 4; ++j) {
    const int col = n0 + wn + j * 16 + ocol;
    const float bj = bias[col];
#pragma unroll
    for (int i = 0; i < 4; ++i) {
      const int rbase = m0 + wm + i * 16 + orow;
#pragma unroll
      for (int r = 0; r < 4; ++r) {
        float v = acc[i][j][r] + bj;
        if (ACT) {
          v = 1.0f / (1.0f + __expf(-v));
          ((u16*)Cv)[(size_t)(rbase + r) * Nc + col] = f2bf(v);
        } else {
          ((float*)Cv)[(size_t)(rbase + r) * Nc + col] = v;
        }
      }
    }
  }
}

// ---------------------------------------------------------------------------
// Covariance: partial[z][a,b] = sum_{n in chunk z} f(P[n,a])*f(Q[n,b]), f(h)=h(1-h).
// P,Q bf16. 64x64 tile / block, split-K over grid.z, no atomics.
// ---------------------------------------------------------------------------
__global__ void covar_bf16(const u16* __restrict__ P, const u16* __restrict__ Q,
                           float* __restrict__ partial, int Ap, int Bq, int chunk) {
  __shared__ float Ps[16][68];
  __shared__ float Qs[16][68];
  const int tid = threadIdx.x;
  const int a0 = blockIdx.x * 64;
  const int b0 = blockIdx.y * 64;
  const int nbase = blockIdx.z * chunk;
  const int tx = tid & 15, ty = tid >> 4;
  float acc[4][4] = {};
  for (int nn = 0; nn < chunk; nn += 16) {
    const int e = tid * 4;
    const int r = e >> 6;
    const int c = e & 63;
    {
      const ushort4 v = *(const ushort4*)(P + (size_t)(nbase + nn + r) * Ap + (a0 + c));
      const float p0 = bf2f(v.x), p1 = bf2f(v.y), p2 = bf2f(v.z), p3 = bf2f(v.w);
      Ps[r][c + 0] = p0 * (1.0f - p0);
      Ps[r][c + 1] = p1 * (1.0f - p1);
      Ps[r][c + 2] = p2 * (1.0f - p2);
      Ps[r][c + 3] = p3 * (1.0f - p3);
    }
    {
      const ushort4 u = *(const ushort4*)(Q + (size_t)(nbase + nn + r) * Bq + (b0 + c));
      const float q0 = bf2f(u.x), q1 = bf2f(u.y), q2 = bf2f(u.z), q3 = bf2f(u.w);
      Qs[r][c + 0] = q0 * (1.0f - q0);
      Qs[r][c + 1] = q1 * (1.0f - q1);
      Qs[r][c + 2] = q2 * (1.0f - q2);
      Qs[r][c + 3] = q3 * (1.0f - q3);
    }
    __syncthreads();
#pragma unroll
    for (int kk = 0; kk < 16; ++kk) {
      float a[4], b[4];
#pragma unroll
      for (int i = 0; i < 4; ++i) a[i] = Ps[kk][ty * 4 + i];
#pragma unroll
      for (int j = 0; j < 4; ++j) b[j] = Qs[kk][tx * 4 + j];
#pragma unroll
      for (int i = 0; i < 4; ++i)
#pragma unroll
        for (int j = 0; j < 4; ++j) acc[i][j] += a[i] * b[j];
    }
    __syncthreads();
  }
  float* out = partial + (size_t)blockIdx.z * Ap * Bq;
#pragma unroll
  for (int i = 0; i < 4; ++i)
#pragma unroll
    for (int j = 0; j < 4; ++j)
      out[(size_t)(a0 + ty * 4 + i) * Bq + (b0 + tx * 4 + j)] = acc[i][j];
}

__global__ void reduce_partial(const float* __restrict__ partial, float* __restrict__ out,
                               int S, int Z) {
  const int i = blockIdx.x * 256 + threadIdx.x;
  float s = 0.f;
  for (int z = 0; z < Z; ++z) s += partial[(size_t)z * S + i];
  out[i] = s;
}

// ---------------------------------------------------------------------------
// z = h2e @ W2 + b2 ; theta(z) ; dzb = theta @ Ew + Eb.  One wave per row.
// ---------------------------------------------------------------------------
__global__ void enc_l3_sindy(const u16* __restrict__ h2, const float* __restrict__ W2,
                             const float* __restrict__ b2, const float* __restrict__ Ew,
                             const float* __restrict__ Eb, float* __restrict__ z_out,
                             float* __restrict__ dzb_out) {
  const int lane = threadIdx.x & 63;
  const int row = blockIdx.x * 4 + (threadIdx.x >> 6);
  const ushort2 h = *(const ushort2*)(h2 + (size_t)row * 128 + lane * 2);
  const float hx = bf2f(h.x), hy = bf2f(h.y);
  const int k = lane * 2;
  float s[3];
#pragma unroll
  for (int l = 0; l < 3; ++l)
    s[l] = hx * W2[k * 3 + l] + hy * W2[(k + 1) * 3 + l];
#pragma unroll
  for (int off = 32; off > 0; off >>= 1) {
    s[0] += __shfl_xor(s[0], off);
    s[1] += __shfl_xor(s[1], off);
    s[2] += __shfl_xor(s[2], off);
  }
  if (lane == 0) {
    const float z0 = s[0] + b2[0];
    const float z1 = s[1] + b2[1];
    const float z2 = s[2] + b2[2];
    z_out[row * 3 + 0] = z0;
    z_out[row * 3 + 1] = z1;
    z_out[row * 3 + 2] = z2;
    float th[22];
    th[0] = 1.f; th[1] = 1.f; th[2] = 1.f;
    th[3] = z0; th[4] = z1; th[5] = z2;
    th[6] = z0 * z0; th[7] = z0 * z1; th[8] = z0 * z2;
    th[9] = z1 * z1; th[10] = z1 * z2; th[11] = z2 * z2;
    th[12] = z0 * z0 * z0; th[13] = z0 * z0 * z1; th[14] = z0 * z0 * z2;
    th[15] = z0 * z1 * z1; th[16] = z0 * z1 * z2; th[17] = z0 * z2 * z2;
    th[18] = z1 * z1 * z1; th[19] = z1 * z1 * z2; th[20] = z1 * z2 * z2;
    th[21] = z2 * z2 * z2;
    float d0 = Eb[0], d1 = Eb[1], d2 = Eb[2];
#pragma unroll
    for (int c = 0; c < 22; ++c) {
      d0 += th[c] * Ew[c * 3 + 0];
      d1 += th[c] * Ew[c * 3 + 1];
      d2 += th[c] * Ew[c * 3 + 2];
    }
    dzb_out[row * 3 + 0] = d0;
    dzb_out[row * 3 + 1] = d1;
    dzb_out[row * 3 + 2] = d2;
  }
}

// T1[l,b] = (1/N) * sum_a W2[a,l] * W1[b,a] * Ce[a,b]
__global__ void t1_kernel(const float* __restrict__ Ce, const float* __restrict__ W2,
                          const float* __restrict__ W1, float* __restrict__ T1) {
  const int l = blockIdx.x;
  const int b = threadIdx.x;
  float acc = 0.f;
  for (int a = 0; a < 128; ++a)
    acc += W2[a * 3 + l] * W1[b * 128 + a] * Ce[a * 256 + b];
  T1[l * 256 + b] = acc * (1.0f / 65536.0f);
}

// Je[l,k] = sum_b T1[l,b] * W0[k,b]  (W0 here = eW0t-like access on fp32 original)
__global__ void je_kernel(const float* __restrict__ T1, const float* __restrict__ W0,
                          float* __restrict__ Je) {
  const int k = blockIdx.x * 256 + threadIdx.x;
  const int l = blockIdx.y;
  float acc = 0.f;
  for (int b = 0; b < 256; ++b) acc += T1[l * 256 + b] * W0[(size_t)k * 256 + b];
  Je[l * 512 + k] = acc;
}

// T2[a,l] = (1/N) * sum_b Cd[a,b] * V1[b,a] * V0[l,b]
__global__ void t2_kernel(const float* __restrict__ Cd, const float* __restrict__ V1,
                          const float* __restrict__ V0, float* __restrict__ T2) {
  const int l = blockIdx.x;
  const int a = threadIdx.x;
  float acc = 0.f;
  for (int b = 0; b < 128; ++b)
    acc += Cd[a * 128 + b] * V1[b * 256 + a] * V0[l * 128 + b];
  T2[a * 3 + l] = acc * (1.0f / 65536.0f);
}

// Jd[k,l] = sum_a V2[a,k] * T2[a,l]
__global__ void jd_kernel(const float* __restrict__ T2, const float* __restrict__ V2,
                          float* __restrict__ Jd) {
  const int k = blockIdx.x * 256 + threadIdx.x;
  const int l = blockIdx.y;
  float acc = 0.f;
  for (int a = 0; a < 256; ++a) acc += V2[(size_t)a * 512 + k] * T2[a * 3 + l];
  Jd[k * 3 + l] = acc;
}

// dz[n,l] = sum_k dx[n,k] * Je[l,k]
__global__ void dz_kernel(const float* __restrict__ dx, const float* __restrict__ Je,
                          float* __restrict__ dz) {
  __shared__ float sJe[1536];
  for (int i = threadIdx.x; i < 1536; i += 256) sJe[i] = Je[i];
  __syncthreads();
  const int lane = threadIdx.x & 63;
  const int row = blockIdx.x * 4 + (threadIdx.x >> 6);
  const int k = lane * 8;
  const float4 v0 = *(const float4*)(dx + (size_t)row * 512 + k);
  const float4 v1 = *(const float4*)(dx + (size_t)row * 512 + k + 4);
  float s[3];
#pragma unroll
  for (int l = 0; l < 3; ++l) {
    const float* j = sJe + l * 512 + k;
    s[l] = v0.x * j[0] + v0.y * j[1] + v0.z * j[2] + v0.w * j[3] +
           v1.x * j[4] + v1.y * j[5] + v1.z * j[6] + v1.w * j[7];
  }
#pragma unroll
  for (int off = 32; off > 0; off >>= 1) {
    s[0] += __shfl_xor(s[0], off);
    s[1] += __shfl_xor(s[1], off);
    s[2] += __shfl_xor(s[2], off);
  }
  if (lane == 0) {
    dz[row * 3 + 0] = s[0];
    dz[row * 3 + 1] = s[1];
    dz[row * 3 + 2] = s[2];
  }
}

// h1d[n,j] = sigmoid(sum_l z[n,l]*V0[l,j] + b0[j]) -> bf16
__global__ void dec_l1(const float* __restrict__ z, const float* __restrict__ V0,
                       const float* __restrict__ b0, u16* __restrict__ h1d) {
  __shared__ float sW[512];
  for (int i = threadIdx.x; i < 512; i += 256)
    sW[i] = (i < 384) ? V0[i] : b0[i - 384];
  __syncthreads();
  const int idx = blockIdx.x * 256 + threadIdx.x;
  const int n = idx >> 7;
  const int j = idx & 127;
  const float z0 = z[n * 3 + 0], z1 = z[n * 3 + 1], z2 = z[n * 3 + 2];
  const float v = z0 * sW[j] + z1 * sW[128 + j] + z2 * sW[256 + j] + sW[384 + j];
  h1d[idx] = f2bf(1.0f / (1.0f + __expf(-v)));
}

// dxb[n,k] = sum_l dzb[n,l] * Jd[k,l]
__global__ void dxb_kernel(const float* __restrict__ dzb, const float* __restrict__ Jd,
                           float* __restrict__ dxb) {
  __shared__ float sJd[1536];
  for (int i = threadIdx.x; i < 1536; i += 256) sJd[i] = Jd[i];
  __syncthreads();
  const int idx = blockIdx.x * 256 + threadIdx.x;
  const int n = idx >> 9;
  const int k = idx & 511;
  const float d0 = dzb[n * 3 + 0], d1 = dzb[n * 3 + 1], d2 = dzb[n * 3 + 2];
  dxb[idx] = d0 * sJd[k * 3 + 0] + d1 * sJd[k * 3 + 1] + d2 * sJd[k * 3 + 2];
}

extern "C" void kernel_launch(void* const* d_in, const int* in_sizes, int n_in,
                              void* d_out, int out_size, void* d_ws, size_t ws_size,
                              hipStream_t stream) {
  const int N = NROWS;
  const float* x   = (const float*)d_in[0];
  const float* dx  = (const float*)d_in[1];
  const float* eW0 = (const float*)d_in[3];
  const float* eb0 = (const float*)d_in[4];
  const float* eW1 = (const float*)d_in[5];
  const float* eb1 = (const float*)d_in[6];
  const float* eW2 = (const float*)d_in[7];
  const float* eb2 = (const float*)d_in[8];
  const float* dW0 = (const float*)d_in[9];
  const float* db0 = (const float*)d_in[10];
  const float* dW1 = (const float*)d_in[11];
  const float* db1 = (const float*)d_in[12];
  const float* dW2 = (const float*)d_in[13];
  const float* db2 = (const float*)d_in[14];
  const float* Ew  = (const float*)d_in[15];
  const float* Eb  = (const float*)d_in[16];

  float* out = (float*)d_out;
  float* z_out   = out;
  float* dz_out  = out + (size_t)N * 3;
  float* dzb_out = out + (size_t)N * 6;
  float* xb_out  = out + (size_t)N * 9;
  float* dxb_out = out + (size_t)N * 9 + (size_t)N * 512;

  // workspace layout (bf16 activations; decoder aliases encoder buffers)
  u16* h1e = (u16*)d_ws;                       // N*256 bf16
  u16* h2e = h1e + (size_t)N * 256;            // N*128 bf16
  u16* h2d = h1e;                              // alias (h1e dead after covarE)
  u16* h1d = h2e;                              // alias (h2e dead after covarE)
  u16* wbuf = h2e + (size_t)N * 128;
  u16* eW0t = wbuf;                            // 256*512
  u16* eW1t = eW0t + 131072;                   // 128*256
  u16* dW1t = eW1t + 32768;                    // 256*128
  u16* dW2t = dW1t + 32768;                    // 512*256
  float* partial = (float*)(dW2t + 131072);    // 128 * 32768 f32 (shared Ce/Cd)
  float* Ce = partial + (size_t)128 * 32768;   // 128*256
  float* Cd = Ce + 32768;                      // 256*128
  float* T1 = Cd + 32768;
  float* T2 = T1 + 768;
  float* Je = T2 + 768;
  float* Jd = Je + 1536;

  prep_weights<<<1280, 256, 0, stream>>>(eW0, eW1, dW1, dW2, eW0t, eW1t, dW1t, dW2t);

  // encoder forward
  gemm_mfma<1, 1><<<dim3(2, N / 128), 256, 0, stream>>>(x, eW0t, eb0, h1e, 512, 256);
  gemm_mfma<1, 0><<<dim3(1, N / 128), 256, 0, stream>>>(h1e, eW1t, eb1, h2e, 256, 128);
  enc_l3_sindy<<<N / 4, 256, 0, stream>>>(h2e, eW2, eb2, Ew, Eb, z_out, dzb_out);

  // encoder mean-Jacobian
  covar_bf16<<<dim3(2, 4, 128), 256, 0, stream>>>(h2e, h1e, partial, 128, 256, N / 128);
  reduce_partial<<<128, 256, 0, stream>>>(partial, Ce, 32768, 128);
  t1_kernel<<<3, 256, 0, stream>>>(Ce, eW2, eW1, T1);
  je_kernel<<<dim3(2, 3), 256, 0, stream>>>(T1, eW0, Je);
  dz_kernel<<<N / 4, 256, 0, stream>>>(dx, Je, dz_out);

  // decoder forward (aliases: h1d<-h2e, h2d<-h1e; safe after covarE)
  dec_l1<<<N * 128 / 256, 256, 0, stream>>>(z_out, dW0, db0, h1d);
  gemm_mfma<1, 0><<<dim3(2, N / 128), 256, 0, stream>>>(h1d, dW1t, db1, h2d, 128, 256);
  gemm_mfma<0, 0><<<dim3(4, N / 128), 256, 0, stream>>>(h2d, dW2t, db2, xb_out, 256, 512);

  // decoder mean-Jacobian
  covar_bf16<<<dim3(4, 2, 128), 256, 0, stream>>>(h2d, h1d, partial, 256, 128, N / 128);
  reduce_partial<<<128, 256, 0, stream>>>(partial, Cd, 32768, 128);
  t2_kernel<<<3, 256, 0, stream>>>(Cd, dW1, dW0, T2);
  jd_kernel<<<dim3(2, 3), 256, 0, stream>>>(T2, dW2, Jd);
  dxb_kernel<<<N * 512 / 256, 256, 0, stream>>>(dzb_out, Jd, dxb_out);
}